// Round 15
// baseline (503.267 us; speedup 1.0000x reference)
//
#include <hip/hip_runtime.h>
#include <hip/hip_bf16.h>
#include <math.h>

// ---------------- graph structure ----------------

__global__ void count_indeg(const int* __restrict__ dst, int e, int* __restrict__ indeg) {
    int i = blockIdx.x * blockDim.x + threadIdx.x;
    if (i < e) atomicAdd(&indeg[dst[i]], 1);
}

// fused setup: dinv + ranges + weight table (i < n) | weight fake-quant (i < nW)
__global__ void setup_misc(const int* __restrict__ indeg, float* __restrict__ dinv,
                           int* __restrict__ start, int* __restrict__ cursor,
                           int* __restrict__ counter,
                           const float* __restrict__ g2, const float* __restrict__ g3,
                           float2* __restrict__ wtab, int n,
                           const float* __restrict__ W1, const float* __restrict__ a1,
                           const float* __restrict__ W2, const float* __restrict__ a2,
                           const float* __restrict__ W3, const float* __restrict__ a3,
                           float* __restrict__ w1q, float* __restrict__ w2q,
                           float* __restrict__ w3q, int n1, int n2, int n3) {
    int i = blockIdx.x * blockDim.x + threadIdx.x;
    if (i < n) {
        int d = indeg[i];
        float ds = 1.0f / sqrtf((float)(d + 1));
        dinv[i] = ds;
        wtab[i] = make_float2(ds * g2[i], ds * g3[i]);   // 400KB: L2-resident
        int s = atomicAdd(counter, d);
        start[i] = s;
        cursor[i] = s;
    }
    const float* w; const float* a; float* o; int k;
    if (i < n1) { w = W1; a = a1; o = w1q; k = i; }
    else if (i < n1 + n2) { w = W2; a = a2; o = w2q; k = i - n1; }
    else if (i < n1 + n2 + n3) { w = W3; a = a3; o = w3q; k = i - n1 - n2; }
    else return;
    float s = a[0];
    float v = w[k] / s;
    v = fminf(fmaxf(v, -8.0f), 7.0f);
    o[k] = rintf(v) * s;   // round-half-even, matches jnp.round
}

// minimal CSR fill: one atomic + one 4B store per edge
__global__ void fill_csr_min(const int* __restrict__ src, const int* __restrict__ dst,
                             int e, int* __restrict__ cursor, int* __restrict__ ssrc, int n) {
    int i = blockIdx.x * blockDim.x + threadIdx.x;
    if (i >= e) return;
    int s = src[i];
    int p = atomicAdd(&cursor[dst[i]], 1);
    if (p >= 0 && p < e) ssrc[p] = ((unsigned)s < (unsigned)n) ? s : -1;
}

// ---------------- GEMM 128-col + optional fused BN-stats partials ----------------

__global__ __launch_bounds__(256) void gemm128_bias(
        const float* __restrict__ A, const float* __restrict__ B,
        const float* __restrict__ bias,
        const float* __restrict__ dinv, const float* __restrict__ colsumS,
        float* __restrict__ C, float* __restrict__ statsP, int M, int K) {
    __shared__ float sA[16][132];
    __shared__ float sB[16][132];
    int tid = threadIdx.x;
    int rowBase = blockIdx.x * 128;
    int tx = tid & 15;
    int ty = tid >> 4;
    float acc[8][8] = {};

    int aRow = tid >> 1;
    int aK   = (tid & 1) * 8;
    int bK   = tid >> 4;
    int bCol = (tid & 15) * 8;

    for (int k0 = 0; k0 < K; k0 += 16) {
        int gRow = rowBase + aRow;
        if (gRow >= M) gRow = M - 1;
        const float* ap = A + (size_t)gRow * K + k0 + aK;
        float4 a0 = *(const float4*)ap;
        float4 a1 = *(const float4*)(ap + 4);
        sA[aK + 0][aRow] = a0.x;
        sA[aK + 1][aRow] = a0.y;
        sA[aK + 2][aRow] = a0.z;
        sA[aK + 3][aRow] = a0.w;
        sA[aK + 4][aRow] = a1.x;
        sA[aK + 5][aRow] = a1.y;
        sA[aK + 6][aRow] = a1.z;
        sA[aK + 7][aRow] = a1.w;
        const float* bp = B + (size_t)(k0 + bK) * 128 + bCol;
        *(float4*)&sB[bK][bCol]     = *(const float4*)bp;
        *(float4*)&sB[bK][bCol + 4] = *(const float4*)(bp + 4);
        __syncthreads();

#pragma unroll
        for (int kk = 0; kk < 16; ++kk) {
            float4 av0 = *(const float4*)&sA[kk][ty * 8];
            float4 av1 = *(const float4*)&sA[kk][ty * 8 + 4];
            float4 bv0 = *(const float4*)&sB[kk][tx * 4];
            float4 bv1 = *(const float4*)&sB[kk][64 + tx * 4];
            float a[8] = {av0.x, av0.y, av0.z, av0.w, av1.x, av1.y, av1.z, av1.w};
            float b[8] = {bv0.x, bv0.y, bv0.z, bv0.w, bv1.x, bv1.y, bv1.z, bv1.w};
#pragma unroll
            for (int i = 0; i < 8; ++i)
#pragma unroll
                for (int j = 0; j < 8; ++j)
                    acc[i][j] = fmaf(a[i], b[j], acc[i][j]);
        }
        __syncthreads();
    }

    int c0 = tx * 4, c1 = 64 + tx * 4;
    float bb[8];
#pragma unroll
    for (int j = 0; j < 4; ++j) { bb[j] = bias[c0 + j]; bb[4 + j] = bias[c1 + j]; }
    float s1[8] = {}, s2[8] = {};
#pragma unroll
    for (int i = 0; i < 8; ++i) {
        int row = rowBase + ty * 8 + i;
        if (row >= M) continue;
        float rs = 1.0f;
        if (dinv) { float di = dinv[row]; rs = di * di + colsumS[row]; }
        float v[8];
#pragma unroll
        for (int j = 0; j < 8; ++j) {
            v[j] = acc[i][j] + rs * bb[j];
            s1[j] += v[j];
            s2[j] += v[j] * v[j];
        }
        *(float4*)&C[(size_t)row * 128 + c0] = *(float4*)&v[0];
        *(float4*)&C[(size_t)row * 128 + c1] = *(float4*)&v[4];
    }
    if (statsP) {
        float* sp = statsP + (blockIdx.x & 63) * 256;
#pragma unroll
        for (int j = 0; j < 4; ++j) { sA[ty][c0 + j] = s1[j]; sA[ty][c1 + j] = s1[4 + j]; }
        __syncthreads();
        if (tid < 128) {
            float t = 0.f;
#pragma unroll
            for (int k = 0; k < 16; ++k) t += sA[k][tid];
            atomicAdd(&sp[tid], t);
        }
        __syncthreads();
#pragma unroll
        for (int j = 0; j < 4; ++j) { sA[ty][c0 + j] = s2[j]; sA[ty][c1 + j] = s2[4 + j]; }
        __syncthreads();
        if (tid < 128) {
            float t = 0.f;
#pragma unroll
            for (int k = 0; k < 16; ++k) t += sA[k][tid];
            atomicAdd(&sp[128 + tid], t);
        }
    }
}

// ---------------- layer-3 GEMM (N<=64) + fused log_softmax ----------------

__global__ __launch_bounds__(256) void gemm40_softmax(
        const float* __restrict__ A, const float* __restrict__ B,
        const float* __restrict__ bias,
        const float* __restrict__ dinv, const float* __restrict__ colsumS,
        float* __restrict__ out, int M, int N, int K) {
    __shared__ float sA[16][132];
    __shared__ float sB[16][68];
    __shared__ float sOut[128][41];
    int tid = threadIdx.x;
    int rowBase = blockIdx.x * 128;
    int tx = tid & 15;
    int ty = tid >> 4;
    float acc[8][4] = {};

    int aRow = tid >> 1;
    int aK   = (tid & 1) * 8;
    int bK   = tid >> 4;
    int bCol = (tid & 15) * 4;

    for (int k0 = 0; k0 < K; k0 += 16) {
        int gRow = rowBase + aRow;
        if (gRow >= M) gRow = M - 1;
        const float* ap = A + (size_t)gRow * K + k0 + aK;
        float4 a0 = *(const float4*)ap;
        float4 a1 = *(const float4*)(ap + 4);
        sA[aK + 0][aRow] = a0.x;
        sA[aK + 1][aRow] = a0.y;
        sA[aK + 2][aRow] = a0.z;
        sA[aK + 3][aRow] = a0.w;
        sA[aK + 4][aRow] = a1.x;
        sA[aK + 5][aRow] = a1.y;
        sA[aK + 6][aRow] = a1.z;
        sA[aK + 7][aRow] = a1.w;
#pragma unroll
        for (int j = 0; j < 4; ++j) {
            int col = bCol + j;
            sB[bK][col] = (col < N) ? B[(size_t)(k0 + bK) * N + col] : 0.0f;
        }
        __syncthreads();
#pragma unroll
        for (int kk = 0; kk < 16; ++kk) {
            float4 av0 = *(const float4*)&sA[kk][ty * 8];
            float4 av1 = *(const float4*)&sA[kk][ty * 8 + 4];
            float4 bv  = *(const float4*)&sB[kk][tx * 4];
            float a[8] = {av0.x, av0.y, av0.z, av0.w, av1.x, av1.y, av1.z, av1.w};
            float b[4] = {bv.x, bv.y, bv.z, bv.w};
#pragma unroll
            for (int i = 0; i < 8; ++i)
#pragma unroll
                for (int j = 0; j < 4; ++j)
                    acc[i][j] = fmaf(a[i], b[j], acc[i][j]);
        }
        __syncthreads();
    }

    int colOut = tx * 4;
    float bb[4];
#pragma unroll
    for (int j = 0; j < 4; ++j) bb[j] = (colOut + j < N) ? bias[colOut + j] : 0.0f;
#pragma unroll
    for (int i = 0; i < 8; ++i) {
        int rowL = ty * 8 + i;
        int row = rowBase + rowL;
        float rs = 1.0f;
        if (row < M) { float di = dinv[row]; rs = di * di + colsumS[row]; }
#pragma unroll
        for (int j = 0; j < 4; ++j)
            if (colOut + j < N) sOut[rowL][colOut + j] = acc[i][j] + rs * bb[j];
    }
    __syncthreads();
    if (tid < 128) {
        int row = rowBase + tid;
        if (row < M) {
            float mx = -INFINITY;
            for (int c = 0; c < N; ++c) mx = fmaxf(mx, sOut[tid][c]);
            float sm = 0.f;
            for (int c = 0; c < N; ++c) sm += expf(sOut[tid][c] - mx);
            float lg = mx + logf(sm);
            float* op = out + (size_t)row * N;
            for (int c = 0; c < N; ++c) op[c] = sOut[tid][c] - lg;
        }
    }
}

// ---------------- fp32 aggregation (layer 1): index-only staging ----------------
// Weight dinv[sa]*di loaded inside the gather loop (parallel with row gather,
// broadcast across slot lanes, 200KB L2-resident table). colsum in-loop.

__global__ __launch_bounds__(256) void aggregate128_par(
        const float* __restrict__ h, const float* __restrict__ dinv,
        const int* __restrict__ start, const int* __restrict__ indeg,
        const int* __restrict__ ssrc, float* __restrict__ out,
        float* __restrict__ colsumS, int n, int E) {
    __shared__ int   sIdx[256];
    __shared__ float red[8][132];
    __shared__ float wpart[4];
    int node = blockIdx.x;
    int tid = threadIdx.x;
    int c4 = (tid & 31) * 4;
    int slot = tid >> 5;
    float di = dinv[node];
    int s0 = start[node];
    int len = indeg[node];
    if (s0 < 0) s0 = 0;
    if (len < 0) len = 0;
    if (s0 + len > E) len = (E - s0 > 0) ? (E - s0) : 0;

    float4 acc = {0.f, 0.f, 0.f, 0.f};
    float wacc = 0.f;
    bool wlane = (tid & 31) == 0;    // one counter lane per slot
    for (int chunk = 0; chunk < len; chunk += 256) {
        int m = len - chunk; if (m > 256) m = 256;
        if (tid < m) {
            int s = ssrc[s0 + chunk + tid];
            if ((unsigned)s >= (unsigned)n) s = -1;
            sIdx[tid] = s;
        }
        __syncthreads();
        int j = slot;
        for (; j + 8 < m; j += 16) {
            int sa = sIdx[j], sb = sIdx[j + 8];
            bool oka = sa >= 0, okb = sb >= 0;
            int ga = oka ? sa : node, gb = okb ? sb : node;
            float wa = oka ? dinv[ga] * di : 0.f;     // parallel with row gather
            float wb = okb ? dinv[gb] * di : 0.f;
            float4 va = *(const float4*)(h + (size_t)ga * 128 + c4);
            float4 vb = *(const float4*)(h + (size_t)gb * 128 + c4);
            if (wlane) wacc += wa + wb;
            acc.x = fmaf(va.x, wa, acc.x); acc.y = fmaf(va.y, wa, acc.y);
            acc.z = fmaf(va.z, wa, acc.z); acc.w = fmaf(va.w, wa, acc.w);
            acc.x = fmaf(vb.x, wb, acc.x); acc.y = fmaf(vb.y, wb, acc.y);
            acc.z = fmaf(vb.z, wb, acc.z); acc.w = fmaf(vb.w, wb, acc.w);
        }
        if (j < m) {
            int sa = sIdx[j];
            bool oka = sa >= 0;
            int ga = oka ? sa : node;
            float wa = oka ? dinv[ga] * di : 0.f;
            float4 va = *(const float4*)(h + (size_t)ga * 128 + c4);
            if (wlane) wacc += wa;
            acc.x = fmaf(va.x, wa, acc.x); acc.y = fmaf(va.y, wa, acc.y);
            acc.z = fmaf(va.z, wa, acc.z); acc.w = fmaf(va.w, wa, acc.w);
        }
        __syncthreads();
    }
#pragma unroll
    for (int o = 1; o < 64; o <<= 1) wacc += __shfl_xor(wacc, o);
    if ((tid & 63) == 0) wpart[tid >> 6] = wacc;
    *(float4*)&red[slot][c4] = acc;
    __syncthreads();
    if (tid == 0) colsumS[node] = wpart[0] + wpart[1] + wpart[2] + wpart[3];
    if (tid < 128) {
        int c = tid;
        float r = h[(size_t)node * 128 + c] * di * di;    // self loop
#pragma unroll
        for (int s = 0; s < 8; ++s) r += red[s][c];
        out[(size_t)node * 128 + c] = r;
    }
}

// ---------------- u8 aggregation (layers 2,3): one WAVE per node ----------------
// Aligned 128B code rows (2 lines); weight from flat float2 wtab (400KB, L2),
// loaded in parallel with the row gather.

__device__ __forceinline__ void unpack_fma(float* acc, uint4 v, float w) {
    acc[0]  = fmaf((float)(v.x & 255), w, acc[0]);
    acc[1]  = fmaf((float)((v.x >> 8) & 255), w, acc[1]);
    acc[2]  = fmaf((float)((v.x >> 16) & 255), w, acc[2]);
    acc[3]  = fmaf((float)(v.x >> 24), w, acc[3]);
    acc[4]  = fmaf((float)(v.y & 255), w, acc[4]);
    acc[5]  = fmaf((float)((v.y >> 8) & 255), w, acc[5]);
    acc[6]  = fmaf((float)((v.y >> 16) & 255), w, acc[6]);
    acc[7]  = fmaf((float)(v.y >> 24), w, acc[7]);
    acc[8]  = fmaf((float)(v.z & 255), w, acc[8]);
    acc[9]  = fmaf((float)((v.z >> 8) & 255), w, acc[9]);
    acc[10] = fmaf((float)((v.z >> 16) & 255), w, acc[10]);
    acc[11] = fmaf((float)(v.z >> 24), w, acc[11]);
    acc[12] = fmaf((float)(v.w & 255), w, acc[12]);
    acc[13] = fmaf((float)((v.w >> 8) & 255), w, acc[13]);
    acc[14] = fmaf((float)((v.w >> 16) & 255), w, acc[14]);
    acc[15] = fmaf((float)(v.w >> 24), w, acc[15]);
}

__global__ __launch_bounds__(256) void aggregate_q8_wave(
        const unsigned char* __restrict__ q, const float* __restrict__ dinv,
        const float* __restrict__ gscale, const float2* __restrict__ wtab, int gsel,
        const int* __restrict__ start, const int* __restrict__ indeg,
        const int* __restrict__ ssrc, float* __restrict__ out, int n, int E) {
    int node = blockIdx.x * 4 + (threadIdx.x >> 6);
    if (node >= n) return;
    int lane = threadIdx.x & 63;
    int slot = lane >> 3;      // 0..7
    int sl   = lane & 7;       // covers bytes sl*16..sl*16+15
    float di = dinv[node];
    int s0 = start[node];
    int len = indeg[node];
    if (s0 < 0) s0 = 0;
    if (len < 0) len = 0;
    if (s0 + len > E) len = (E - s0 > 0) ? (E - s0) : 0;

    float acc[16] = {};
    int j = slot;
    for (; j + 8 < len; j += 16) {
        int sa = ssrc[s0 + j];
        int sb = ssrc[s0 + j + 8];
        bool oka = (unsigned)sa < (unsigned)n;
        bool okb = (unsigned)sb < (unsigned)n;
        if (!oka) sa = node;
        if (!okb) sb = node;
        float2 wva = wtab[sa];                        // parallel with row gather
        float2 wvb = wtab[sb];
        float wa = oka ? (gsel ? wva.y : wva.x) * di : 0.f;
        float wb = okb ? (gsel ? wvb.y : wvb.x) * di : 0.f;
        uint4 va = *(const uint4*)(q + (size_t)sa * 128 + sl * 16);
        uint4 vb = *(const uint4*)(q + (size_t)sb * 128 + sl * 16);
        unpack_fma(acc, va, wa);
        unpack_fma(acc, vb, wb);
    }
    if (j < len) {
        int sa = ssrc[s0 + j];
        bool oka = (unsigned)sa < (unsigned)n;
        if (!oka) sa = node;
        float2 wva = wtab[sa];
        float wa = oka ? (gsel ? wva.y : wva.x) * di : 0.f;
        uint4 va = *(const uint4*)(q + (size_t)sa * 128 + sl * 16);
        unpack_fma(acc, va, wa);
    }
#pragma unroll
    for (int o = 8; o < 64; o <<= 1) {
#pragma unroll
        for (int k = 0; k < 16; ++k) acc[k] += __shfl_xor(acc[k], o);
    }
    if (slot == 0) {
        uint4 vs = *(const uint4*)(q + (size_t)node * 128 + sl * 16);
        unpack_fma(acc, vs, gscale[node] * di * di);   // self loop
        float* op = out + (size_t)node * 128 + sl * 16;
        *(float4*)(op + 0)  = *(float4*)&acc[0];
        *(float4*)(op + 4)  = *(float4*)&acc[4];
        *(float4*)(op + 8)  = *(float4*)&acc[8];
        *(float4*)(op + 12) = *(float4*)&acc[12];
    }
}

// ---------------- BatchNorm ----------------

__global__ void bn_stats(const float* __restrict__ x, int n,
                         float* __restrict__ sums, float* __restrict__ sumsq) {
    int c = threadIdx.x;   // 128
    float s = 0.f, s2 = 0.f;
    for (int r = blockIdx.x; r < n; r += gridDim.x) {
        float v = x[(size_t)r * 128 + c];
        s += v; s2 += v * v;
    }
    atomicAdd(&sums[c], s);
    atomicAdd(&sumsq[c], s2);
}

__global__ void bn_reduce(float* __restrict__ statsP) {
    int t = threadIdx.x;   // 256
    float s = 0.f;
    for (int k = 0; k < 64; ++k) s += statsP[k * 256 + t];
    __syncthreads();
    statsP[t] = s;
}

// BN finalize (per-thread) + affine + ReLU + 4-bit fake-quant -> u8 code (0..15)
__global__ void bn_apply_quant_u8(const float* __restrict__ x,
                                  const float* __restrict__ sums,
                                  const float* __restrict__ sumsq,
                                  const float* __restrict__ g, const float* __restrict__ b,
                                  const float* __restrict__ gs,
                                  unsigned char* __restrict__ out, int n) {
    int idx = blockIdx.x * blockDim.x + threadIdx.x;
    if (idx >= n * 128) return;
    int c = idx & 127;
    int r = idx >> 7;
    float m  = sums[c] / (float)n;
    float vr = sumsq[c] / (float)n - m * m;
    float a  = g[c] * (1.0f / sqrtf(vr + 1e-5f));
    float bp = b[c] - m * a;
    float v = a * x[idx] + bp;
    v = fmaxf(v, 0.0f);
    float qv = fminf(fmaxf(v / gs[r], 0.0f), 15.0f);
    out[idx] = (unsigned char)rintf(qv);   // round-half-even
}

// ---------------- launch ----------------

extern "C" void kernel_launch(void* const* d_in, const int* in_sizes, int n_in,
                              void* d_out, int out_size, void* d_ws, size_t ws_size,
                              hipStream_t stream) {
    float*       xbuf = (float*)d_in[0];          // reused as scratch after layer-1 GEMM
    const int*   ei   = (const int*)d_in[1];
    const float* W1   = (const float*)d_in[2];
    const float* b1   = (const float*)d_in[3];
    const float* a1   = (const float*)d_in[4];
    const float* W2   = (const float*)d_in[5];
    const float* b2   = (const float*)d_in[6];
    const float* a2   = (const float*)d_in[7];
    const float* g2   = (const float*)d_in[8];
    const float* W3   = (const float*)d_in[9];
    const float* b3   = (const float*)d_in[10];
    const float* a3   = (const float*)d_in[11];
    const float* g3   = (const float*)d_in[12];
    const float* bn1g = (const float*)d_in[13];
    const float* bn1b = (const float*)d_in[14];
    const float* bn2g = (const float*)d_in[15];
    const float* bn2b = (const float*)d_in[16];

    const int n = in_sizes[0] / 128;      // 50000
    const int E = in_sizes[1] / 2;        // 800000
    const int C = in_sizes[9] / 128;      // 40
    const int* src = ei;
    const int* dst = ei + E;

    // ---- workspace layout: zeroed region FIRST ----
    char* wsp = (char*)d_ws;
    size_t off = 0;
    auto take = [&](size_t bytes) -> void* {
        void* p = wsp + off;
        off += (bytes + 255) & ~(size_t)255;
        return p;
    };
    int*   indeg   = (int*)take((size_t)n * 4);
    int*   counter = (int*)take(4);
    float* stats1  = (float*)take(256 * 4);          // layer-1: sums | sumsq
    float* stats2  = (float*)take(64 * 256 * 4);     // layer-2: 64 partial copies
    size_t zeroBytes = off;
    int*   startA  = (int*)take((size_t)n * 4);
    int*   cursor  = (int*)take((size_t)n * 4);
    float* dinv    = (float*)take((size_t)n * 4);
    float* colsumS = (float*)take((size_t)n * 4);
    float2* wtab   = (float2*)take((size_t)n * 8);
    int*   ssrc    = (int*)take((size_t)E * 4);
    float* w1q     = (float*)take(128 * 128 * 4);
    float* w2q     = (float*)take(128 * 128 * 4);
    float* w3q     = (float*)take((size_t)128 * C * 4);
    unsigned char* qbuf = (unsigned char*)take((size_t)n * 128);
    float* hbuf    = (float*)take((size_t)n * 128 * 4);

    float* outF  = (float*)d_out;

    // ---- setup ----
    hipMemsetAsync(d_ws, 0, zeroBytes, stream);
    count_indeg<<<(E + 255) / 256, 256, 0, stream>>>(dst, E, indeg);
    const int nW = 128 * 128 + 128 * 128 + 128 * C;
    int setupN = (n > nW) ? n : nW;
    setup_misc<<<(setupN + 255) / 256, 256, 0, stream>>>(
        indeg, dinv, startA, cursor, counter, g2, g3, wtab, n,
        W1, a1, W2, a2, W3, a3, w1q, w2q, w3q, 128 * 128, 128 * 128, 128 * C);
    fill_csr_min<<<(E + 255) / 256, 256, 0, stream>>>(src, dst, E, cursor, ssrc, n);

    const int gElem128 = (n * 128 + 255) / 256;
    const int gWave = (n + 3) / 4;
    const int gRow128 = (n + 127) / 128;

    // ---- layer 1 ----
    gemm128_bias<<<gRow128, 256, 0, stream>>>(xbuf, w1q, b1, nullptr, nullptr,
                                              hbuf, nullptr, n, 128);
    aggregate128_par<<<n, 256, 0, stream>>>(hbuf, dinv, startA, indeg, ssrc,
                                            xbuf, colsumS, n, E);
    bn_stats<<<512, 128, 0, stream>>>(xbuf, n, stats1, stats1 + 128);
    bn_apply_quant_u8<<<gElem128, 256, 0, stream>>>(xbuf, stats1, stats1 + 128,
                                                    bn1g, bn1b, g2, qbuf, n);

    // ---- layer 2: aggregate(q)*W + rowsum*b (stats fused into GEMM) ----
    aggregate_q8_wave<<<gWave, 256, 0, stream>>>(qbuf, dinv, g2, wtab, 0, startA, indeg,
                                                 ssrc, hbuf, n, E);
    gemm128_bias<<<gRow128, 256, 0, stream>>>(hbuf, w2q, b2, dinv, colsumS,
                                              xbuf, stats2, n, 128);
    bn_reduce<<<1, 256, 0, stream>>>(stats2);
    bn_apply_quant_u8<<<gElem128, 256, 0, stream>>>(xbuf, stats2, stats2 + 128,
                                                    bn2g, bn2b, g3, qbuf, n);

    // ---- layer 3: aggregate(q)*W3 + rowsum*b3, softmax fused ----
    aggregate_q8_wave<<<gWave, 256, 0, stream>>>(qbuf, dinv, g3, wtab, 1, startA, indeg,
                                                 ssrc, hbuf, n, E);
    gemm40_softmax<<<gRow128, 256, 0, stream>>>(hbuf, w3q, b3, dinv, colsumS,
                                                outF, n, C, 128);
}

// Round 16
// 467.414 us; speedup vs baseline: 1.0767x; 1.0767x over previous
//
#include <hip/hip_runtime.h>
#include <hip/hip_bf16.h>
#include <math.h>

// ---------------- graph structure ----------------

__global__ void count_indeg(const int* __restrict__ dst, int e, int* __restrict__ indeg) {
    int i = blockIdx.x * blockDim.x + threadIdx.x;
    if (i < e) atomicAdd(&indeg[dst[i]], 1);
}

// fused setup: dinv + ranges + weight table (i < n) | weight fake-quant (i < nW)
__global__ void setup_misc(const int* __restrict__ indeg, float* __restrict__ dinv,
                           int* __restrict__ start, int* __restrict__ cursor,
                           int* __restrict__ counter,
                           const float* __restrict__ g2, const float* __restrict__ g3,
                           float2* __restrict__ wtab, int n,
                           const float* __restrict__ W1, const float* __restrict__ a1,
                           const float* __restrict__ W2, const float* __restrict__ a2,
                           const float* __restrict__ W3, const float* __restrict__ a3,
                           float* __restrict__ w1q, float* __restrict__ w2q,
                           float* __restrict__ w3q, int n1, int n2, int n3) {
    int i = blockIdx.x * blockDim.x + threadIdx.x;
    if (i < n) {
        int d = indeg[i];
        float ds = 1.0f / sqrtf((float)(d + 1));
        dinv[i] = ds;
        wtab[i] = make_float2(ds * g2[i], ds * g3[i]);   // 400KB: L2-resident
        int s = atomicAdd(counter, d);
        start[i] = s;
        cursor[i] = s;
    }
    const float* w; const float* a; float* o; int k;
    if (i < n1) { w = W1; a = a1; o = w1q; k = i; }
    else if (i < n1 + n2) { w = W2; a = a2; o = w2q; k = i - n1; }
    else if (i < n1 + n2 + n3) { w = W3; a = a3; o = w3q; k = i - n1 - n2; }
    else return;
    float s = a[0];
    float v = w[k] / s;
    v = fminf(fmaxf(v, -8.0f), 7.0f);
    o[k] = rintf(v) * s;   // round-half-even, matches jnp.round
}

// minimal CSR fill: one atomic + one 4B store per edge
__global__ void fill_csr_min(const int* __restrict__ src, const int* __restrict__ dst,
                             int e, int* __restrict__ cursor, int* __restrict__ ssrc, int n) {
    int i = blockIdx.x * blockDim.x + threadIdx.x;
    if (i >= e) return;
    int s = src[i];
    int p = atomicAdd(&cursor[dst[i]], 1);
    if (p >= 0 && p < e) ssrc[p] = ((unsigned)s < (unsigned)n) ? s : -1;
}

// ---------------- GEMM 128-col + optional fused BN-stats partials ----------------

__global__ __launch_bounds__(256) void gemm128_bias(
        const float* __restrict__ A, const float* __restrict__ B,
        const float* __restrict__ bias,
        const float* __restrict__ dinv, const float* __restrict__ colsumS,
        float* __restrict__ C, float* __restrict__ statsP, int M, int K) {
    __shared__ float sA[16][132];
    __shared__ float sB[16][132];
    int tid = threadIdx.x;
    int rowBase = blockIdx.x * 128;
    int tx = tid & 15;
    int ty = tid >> 4;
    float acc[8][8] = {};

    int aRow = tid >> 1;
    int aK   = (tid & 1) * 8;
    int bK   = tid >> 4;
    int bCol = (tid & 15) * 8;

    for (int k0 = 0; k0 < K; k0 += 16) {
        int gRow = rowBase + aRow;
        if (gRow >= M) gRow = M - 1;
        const float* ap = A + (size_t)gRow * K + k0 + aK;
        float4 a0 = *(const float4*)ap;
        float4 a1 = *(const float4*)(ap + 4);
        sA[aK + 0][aRow] = a0.x;
        sA[aK + 1][aRow] = a0.y;
        sA[aK + 2][aRow] = a0.z;
        sA[aK + 3][aRow] = a0.w;
        sA[aK + 4][aRow] = a1.x;
        sA[aK + 5][aRow] = a1.y;
        sA[aK + 6][aRow] = a1.z;
        sA[aK + 7][aRow] = a1.w;
        const float* bp = B + (size_t)(k0 + bK) * 128 + bCol;
        *(float4*)&sB[bK][bCol]     = *(const float4*)bp;
        *(float4*)&sB[bK][bCol + 4] = *(const float4*)(bp + 4);
        __syncthreads();

#pragma unroll
        for (int kk = 0; kk < 16; ++kk) {
            float4 av0 = *(const float4*)&sA[kk][ty * 8];
            float4 av1 = *(const float4*)&sA[kk][ty * 8 + 4];
            float4 bv0 = *(const float4*)&sB[kk][tx * 4];
            float4 bv1 = *(const float4*)&sB[kk][64 + tx * 4];
            float a[8] = {av0.x, av0.y, av0.z, av0.w, av1.x, av1.y, av1.z, av1.w};
            float b[8] = {bv0.x, bv0.y, bv0.z, bv0.w, bv1.x, bv1.y, bv1.z, bv1.w};
#pragma unroll
            for (int i = 0; i < 8; ++i)
#pragma unroll
                for (int j = 0; j < 8; ++j)
                    acc[i][j] = fmaf(a[i], b[j], acc[i][j]);
        }
        __syncthreads();
    }

    int c0 = tx * 4, c1 = 64 + tx * 4;
    float bb[8];
#pragma unroll
    for (int j = 0; j < 4; ++j) { bb[j] = bias[c0 + j]; bb[4 + j] = bias[c1 + j]; }
    float s1[8] = {}, s2[8] = {};
#pragma unroll
    for (int i = 0; i < 8; ++i) {
        int row = rowBase + ty * 8 + i;
        if (row >= M) continue;
        float rs = 1.0f;
        if (dinv) { float di = dinv[row]; rs = di * di + colsumS[row]; }
        float v[8];
#pragma unroll
        for (int j = 0; j < 8; ++j) {
            v[j] = acc[i][j] + rs * bb[j];
            s1[j] += v[j];
            s2[j] += v[j] * v[j];
        }
        *(float4*)&C[(size_t)row * 128 + c0] = *(float4*)&v[0];
        *(float4*)&C[(size_t)row * 128 + c1] = *(float4*)&v[4];
    }
    if (statsP) {
        float* sp = statsP + (blockIdx.x & 63) * 256;
#pragma unroll
        for (int j = 0; j < 4; ++j) { sA[ty][c0 + j] = s1[j]; sA[ty][c1 + j] = s1[4 + j]; }
        __syncthreads();
        if (tid < 128) {
            float t = 0.f;
#pragma unroll
            for (int k = 0; k < 16; ++k) t += sA[k][tid];
            atomicAdd(&sp[tid], t);
        }
        __syncthreads();
#pragma unroll
        for (int j = 0; j < 4; ++j) { sA[ty][c0 + j] = s2[j]; sA[ty][c1 + j] = s2[4 + j]; }
        __syncthreads();
        if (tid < 128) {
            float t = 0.f;
#pragma unroll
            for (int k = 0; k < 16; ++k) t += sA[k][tid];
            atomicAdd(&sp[128 + tid], t);
        }
    }
}

// ---------------- layer-3 GEMM (N<=64) + fused log_softmax ----------------

__global__ __launch_bounds__(256) void gemm40_softmax(
        const float* __restrict__ A, const float* __restrict__ B,
        const float* __restrict__ bias,
        const float* __restrict__ dinv, const float* __restrict__ colsumS,
        float* __restrict__ out, int M, int N, int K) {
    __shared__ float sA[16][132];
    __shared__ float sB[16][68];
    __shared__ float sOut[128][41];
    int tid = threadIdx.x;
    int rowBase = blockIdx.x * 128;
    int tx = tid & 15;
    int ty = tid >> 4;
    float acc[8][4] = {};

    int aRow = tid >> 1;
    int aK   = (tid & 1) * 8;
    int bK   = tid >> 4;
    int bCol = (tid & 15) * 4;

    for (int k0 = 0; k0 < K; k0 += 16) {
        int gRow = rowBase + aRow;
        if (gRow >= M) gRow = M - 1;
        const float* ap = A + (size_t)gRow * K + k0 + aK;
        float4 a0 = *(const float4*)ap;
        float4 a1 = *(const float4*)(ap + 4);
        sA[aK + 0][aRow] = a0.x;
        sA[aK + 1][aRow] = a0.y;
        sA[aK + 2][aRow] = a0.z;
        sA[aK + 3][aRow] = a0.w;
        sA[aK + 4][aRow] = a1.x;
        sA[aK + 5][aRow] = a1.y;
        sA[aK + 6][aRow] = a1.z;
        sA[aK + 7][aRow] = a1.w;
#pragma unroll
        for (int j = 0; j < 4; ++j) {
            int col = bCol + j;
            sB[bK][col] = (col < N) ? B[(size_t)(k0 + bK) * N + col] : 0.0f;
        }
        __syncthreads();
#pragma unroll
        for (int kk = 0; kk < 16; ++kk) {
            float4 av0 = *(const float4*)&sA[kk][ty * 8];
            float4 av1 = *(const float4*)&sA[kk][ty * 8 + 4];
            float4 bv  = *(const float4*)&sB[kk][tx * 4];
            float a[8] = {av0.x, av0.y, av0.z, av0.w, av1.x, av1.y, av1.z, av1.w};
            float b[4] = {bv.x, bv.y, bv.z, bv.w};
#pragma unroll
            for (int i = 0; i < 8; ++i)
#pragma unroll
                for (int j = 0; j < 4; ++j)
                    acc[i][j] = fmaf(a[i], b[j], acc[i][j]);
        }
        __syncthreads();
    }

    int colOut = tx * 4;
    float bb[4];
#pragma unroll
    for (int j = 0; j < 4; ++j) bb[j] = (colOut + j < N) ? bias[colOut + j] : 0.0f;
#pragma unroll
    for (int i = 0; i < 8; ++i) {
        int rowL = ty * 8 + i;
        int row = rowBase + rowL;
        float rs = 1.0f;
        if (row < M) { float di = dinv[row]; rs = di * di + colsumS[row]; }
#pragma unroll
        for (int j = 0; j < 4; ++j)
            if (colOut + j < N) sOut[rowL][colOut + j] = acc[i][j] + rs * bb[j];
    }
    __syncthreads();
    if (tid < 128) {
        int row = rowBase + tid;
        if (row < M) {
            float mx = -INFINITY;
            for (int c = 0; c < N; ++c) mx = fmaxf(mx, sOut[tid][c]);
            float sm = 0.f;
            for (int c = 0; c < N; ++c) sm += expf(sOut[tid][c] - mx);
            float lg = mx + logf(sm);
            float* op = out + (size_t)row * N;
            for (int c = 0; c < N; ++c) op[c] = sOut[tid][c] - lg;
        }
    }
}

// ---------------- fp32 aggregation (layer 1): staged flat-dinv weights ----------------
// Round-11 structure (fused BN-stats partials + colsumS) with round-14 staging
// (weight gathered once per edge from the 200KB L2-resident dinv table).

__global__ __launch_bounds__(256) void aggregate128_par(
        const float* __restrict__ h, const float* __restrict__ dinv,
        const int* __restrict__ start, const int* __restrict__ indeg,
        const int* __restrict__ ssrc, float* __restrict__ out,
        float* __restrict__ statsP, float* __restrict__ colsumS, int n, int E) {
    __shared__ int   sIdx[256];
    __shared__ float sW[256];
    __shared__ float red[8][132];
    __shared__ float wpart[4];
    int node = blockIdx.x;
    int tid = threadIdx.x;
    int c4 = (tid & 31) * 4;
    int slot = tid >> 5;
    float di = dinv[node];
    int s0 = start[node];
    int len = indeg[node];
    if (s0 < 0) s0 = 0;
    if (len < 0) len = 0;
    if (s0 + len > E) len = (E - s0 > 0) ? (E - s0) : 0;

    float4 acc = {0.f, 0.f, 0.f, 0.f};
    float wacc = 0.f;
    for (int chunk = 0; chunk < len; chunk += 256) {
        int m = len - chunk; if (m > 256) m = 256;
        if (tid < m) {
            int s = ssrc[s0 + chunk + tid];
            float w;
            if ((unsigned)s >= (unsigned)n) { s = node; w = 0.f; }
            else w = dinv[s] * di;          // flat 200KB table: L2-resident
            sIdx[tid] = s; sW[tid] = w; wacc += w;
        }
        __syncthreads();
        int j = slot;
        for (; j + 8 < m; j += 16) {
            int sa = sIdx[j], sb = sIdx[j + 8];
            float wa = sW[j], wb = sW[j + 8];
            float4 va = *(const float4*)(h + (size_t)sa * 128 + c4);
            float4 vb = *(const float4*)(h + (size_t)sb * 128 + c4);
            acc.x = fmaf(va.x, wa, acc.x); acc.y = fmaf(va.y, wa, acc.y);
            acc.z = fmaf(va.z, wa, acc.z); acc.w = fmaf(va.w, wa, acc.w);
            acc.x = fmaf(vb.x, wb, acc.x); acc.y = fmaf(vb.y, wb, acc.y);
            acc.z = fmaf(vb.z, wb, acc.z); acc.w = fmaf(vb.w, wb, acc.w);
        }
        if (j < m) {
            int sa = sIdx[j];
            float wa = sW[j];
            float4 va = *(const float4*)(h + (size_t)sa * 128 + c4);
            acc.x = fmaf(va.x, wa, acc.x); acc.y = fmaf(va.y, wa, acc.y);
            acc.z = fmaf(va.z, wa, acc.z); acc.w = fmaf(va.w, wa, acc.w);
        }
        __syncthreads();
    }
#pragma unroll
    for (int o = 1; o < 64; o <<= 1) wacc += __shfl_xor(wacc, o);
    if ((tid & 63) == 0) wpart[tid >> 6] = wacc;
    *(float4*)&red[slot][c4] = acc;
    __syncthreads();
    if (tid == 0) colsumS[node] = wpart[0] + wpart[1] + wpart[2] + wpart[3];
    if (tid < 128) {
        int c = tid;
        float r = h[(size_t)node * 128 + c] * di * di;    // self loop
#pragma unroll
        for (int s = 0; s < 8; ++s) r += red[s][c];
        out[(size_t)node * 128 + c] = r;
        float* sp = statsP + (blockIdx.x & 63) * 256;     // fused BN-stats partials
        atomicAdd(&sp[c], r);
        atomicAdd(&sp[128 + c], r * r);
    }
}

// ---------------- u8 aggregation (layers 2,3): one WAVE per node ----------------
// Aligned 128B code rows (2 lines); weight from flat float2 wtab (400KB, L2).

__device__ __forceinline__ void unpack_fma(float* acc, uint4 v, float w) {
    acc[0]  = fmaf((float)(v.x & 255), w, acc[0]);
    acc[1]  = fmaf((float)((v.x >> 8) & 255), w, acc[1]);
    acc[2]  = fmaf((float)((v.x >> 16) & 255), w, acc[2]);
    acc[3]  = fmaf((float)(v.x >> 24), w, acc[3]);
    acc[4]  = fmaf((float)(v.y & 255), w, acc[4]);
    acc[5]  = fmaf((float)((v.y >> 8) & 255), w, acc[5]);
    acc[6]  = fmaf((float)((v.y >> 16) & 255), w, acc[6]);
    acc[7]  = fmaf((float)(v.y >> 24), w, acc[7]);
    acc[8]  = fmaf((float)(v.z & 255), w, acc[8]);
    acc[9]  = fmaf((float)((v.z >> 8) & 255), w, acc[9]);
    acc[10] = fmaf((float)((v.z >> 16) & 255), w, acc[10]);
    acc[11] = fmaf((float)(v.z >> 24), w, acc[11]);
    acc[12] = fmaf((float)(v.w & 255), w, acc[12]);
    acc[13] = fmaf((float)((v.w >> 8) & 255), w, acc[13]);
    acc[14] = fmaf((float)((v.w >> 16) & 255), w, acc[14]);
    acc[15] = fmaf((float)(v.w >> 24), w, acc[15]);
}

__global__ __launch_bounds__(256) void aggregate_q8_wave(
        const unsigned char* __restrict__ q, const float* __restrict__ dinv,
        const float* __restrict__ gscale, const float2* __restrict__ wtab, int gsel,
        const int* __restrict__ start, const int* __restrict__ indeg,
        const int* __restrict__ ssrc, float* __restrict__ out, int n, int E) {
    int node = blockIdx.x * 4 + (threadIdx.x >> 6);
    if (node >= n) return;
    int lane = threadIdx.x & 63;
    int slot = lane >> 3;      // 0..7
    int sl   = lane & 7;       // covers bytes sl*16..sl*16+15
    float di = dinv[node];
    int s0 = start[node];
    int len = indeg[node];
    if (s0 < 0) s0 = 0;
    if (len < 0) len = 0;
    if (s0 + len > E) len = (E - s0 > 0) ? (E - s0) : 0;

    float acc[16] = {};
    int j = slot;
    for (; j + 8 < len; j += 16) {
        int sa = ssrc[s0 + j];
        int sb = ssrc[s0 + j + 8];
        bool oka = (unsigned)sa < (unsigned)n;
        bool okb = (unsigned)sb < (unsigned)n;
        if (!oka) sa = node;
        if (!okb) sb = node;
        float2 wva = wtab[sa];                        // parallel with row gather
        float2 wvb = wtab[sb];
        float wa = oka ? (gsel ? wva.y : wva.x) * di : 0.f;
        float wb = okb ? (gsel ? wvb.y : wvb.x) * di : 0.f;
        uint4 va = *(const uint4*)(q + (size_t)sa * 128 + sl * 16);
        uint4 vb = *(const uint4*)(q + (size_t)sb * 128 + sl * 16);
        unpack_fma(acc, va, wa);
        unpack_fma(acc, vb, wb);
    }
    if (j < len) {
        int sa = ssrc[s0 + j];
        bool oka = (unsigned)sa < (unsigned)n;
        if (!oka) sa = node;
        float2 wva = wtab[sa];
        float wa = oka ? (gsel ? wva.y : wva.x) * di : 0.f;
        uint4 va = *(const uint4*)(q + (size_t)sa * 128 + sl * 16);
        unpack_fma(acc, va, wa);
    }
#pragma unroll
    for (int o = 8; o < 64; o <<= 1) {
#pragma unroll
        for (int k = 0; k < 16; ++k) acc[k] += __shfl_xor(acc[k], o);
    }
    if (slot == 0) {
        uint4 vs = *(const uint4*)(q + (size_t)node * 128 + sl * 16);
        unpack_fma(acc, vs, gscale[node] * di * di);   // self loop
        float* op = out + (size_t)node * 128 + sl * 16;
        *(float4*)(op + 0)  = *(float4*)&acc[0];
        *(float4*)(op + 4)  = *(float4*)&acc[4];
        *(float4*)(op + 8)  = *(float4*)&acc[8];
        *(float4*)(op + 12) = *(float4*)&acc[12];
    }
}

// ---------------- BN partial reduce: 64 copies -> copy 0 ----------------

__global__ void bn_reduce(float* __restrict__ statsP) {
    int t = threadIdx.x;   // 256
    float s = 0.f;
    for (int k = 0; k < 64; ++k) s += statsP[k * 256 + t];
    __syncthreads();
    statsP[t] = s;
}

// BN finalize (per-thread) + affine + ReLU + 4-bit fake-quant -> u8 code (0..15)
__global__ void bn_apply_quant_u8(const float* __restrict__ x,
                                  const float* __restrict__ sums,
                                  const float* __restrict__ sumsq,
                                  const float* __restrict__ g, const float* __restrict__ b,
                                  const float* __restrict__ gs,
                                  unsigned char* __restrict__ out, int n) {
    int idx = blockIdx.x * blockDim.x + threadIdx.x;
    if (idx >= n * 128) return;
    int c = idx & 127;
    int r = idx >> 7;
    float m  = sums[c] / (float)n;
    float vr = sumsq[c] / (float)n - m * m;
    float a  = g[c] * (1.0f / sqrtf(vr + 1e-5f));
    float bp = b[c] - m * a;
    float v = a * x[idx] + bp;
    v = fmaxf(v, 0.0f);
    float qv = fminf(fmaxf(v / gs[r], 0.0f), 15.0f);
    out[idx] = (unsigned char)rintf(qv);   // round-half-even
}

// ---------------- launch ----------------

extern "C" void kernel_launch(void* const* d_in, const int* in_sizes, int n_in,
                              void* d_out, int out_size, void* d_ws, size_t ws_size,
                              hipStream_t stream) {
    float*       xbuf = (float*)d_in[0];          // reused as scratch after layer-1 GEMM
    const int*   ei   = (const int*)d_in[1];
    const float* W1   = (const float*)d_in[2];
    const float* b1   = (const float*)d_in[3];
    const float* a1   = (const float*)d_in[4];
    const float* W2   = (const float*)d_in[5];
    const float* b2   = (const float*)d_in[6];
    const float* a2   = (const float*)d_in[7];
    const float* g2   = (const float*)d_in[8];
    const float* W3   = (const float*)d_in[9];
    const float* b3   = (const float*)d_in[10];
    const float* a3   = (const float*)d_in[11];
    const float* g3   = (const float*)d_in[12];
    const float* bn1g = (const float*)d_in[13];
    const float* bn1b = (const float*)d_in[14];
    const float* bn2g = (const float*)d_in[15];
    const float* bn2b = (const float*)d_in[16];

    const int n = in_sizes[0] / 128;      // 50000
    const int E = in_sizes[1] / 2;        // 800000
    const int C = in_sizes[9] / 128;      // 40
    const int* src = ei;
    const int* dst = ei + E;

    // ---- workspace layout: zeroed region FIRST ----
    char* wsp = (char*)d_ws;
    size_t off = 0;
    auto take = [&](size_t bytes) -> void* {
        void* p = wsp + off;
        off += (bytes + 255) & ~(size_t)255;
        return p;
    };
    int*   indeg   = (int*)take((size_t)n * 4);
    int*   counter = (int*)take(4);
    float* stats1  = (float*)take(64 * 256 * 4);     // layer-1: 64 partial copies
    float* stats2  = (float*)take(64 * 256 * 4);     // layer-2: 64 partial copies
    size_t zeroBytes = off;
    int*   startA  = (int*)take((size_t)n * 4);
    int*   cursor  = (int*)take((size_t)n * 4);
    float* dinv    = (float*)take((size_t)n * 4);
    float* colsumS = (float*)take((size_t)n * 4);
    float2* wtab   = (float2*)take((size_t)n * 8);
    int*   ssrc    = (int*)take((size_t)E * 4);
    float* w1q     = (float*)take(128 * 128 * 4);
    float* w2q     = (float*)take(128 * 128 * 4);
    float* w3q     = (float*)take((size_t)128 * C * 4);
    unsigned char* qbuf = (unsigned char*)take((size_t)n * 128);
    float* hbuf    = (float*)take((size_t)n * 128 * 4);

    float* outF  = (float*)d_out;

    // ---- setup ----
    hipMemsetAsync(d_ws, 0, zeroBytes, stream);
    count_indeg<<<(E + 255) / 256, 256, 0, stream>>>(dst, E, indeg);
    const int nW = 128 * 128 + 128 * 128 + 128 * C;
    int setupN = (n > nW) ? n : nW;
    setup_misc<<<(setupN + 255) / 256, 256, 0, stream>>>(
        indeg, dinv, startA, cursor, counter, g2, g3, wtab, n,
        W1, a1, W2, a2, W3, a3, w1q, w2q, w3q, 128 * 128, 128 * 128, 128 * C);
    fill_csr_min<<<(E + 255) / 256, 256, 0, stream>>>(src, dst, E, cursor, ssrc, n);

    const int gElem128 = (n * 128 + 255) / 256;
    const int gWave = (n + 3) / 4;
    const int gRow128 = (n + 127) / 128;

    // ---- layer 1 (stats fused into aggregate, as in round 11) ----
    gemm128_bias<<<gRow128, 256, 0, stream>>>(xbuf, w1q, b1, nullptr, nullptr,
                                              hbuf, nullptr, n, 128);
    aggregate128_par<<<n, 256, 0, stream>>>(hbuf, dinv, startA, indeg, ssrc,
                                            xbuf, stats1, colsumS, n, E);
    bn_reduce<<<1, 256, 0, stream>>>(stats1);
    bn_apply_quant_u8<<<gElem128, 256, 0, stream>>>(xbuf, stats1, stats1 + 128,
                                                    bn1g, bn1b, g2, qbuf, n);

    // ---- layer 2: aggregate(q)*W + rowsum*b (stats fused into GEMM) ----
    aggregate_q8_wave<<<gWave, 256, 0, stream>>>(qbuf, dinv, g2, wtab, 0, startA, indeg,
                                                 ssrc, hbuf, n, E);
    gemm128_bias<<<gRow128, 256, 0, stream>>>(hbuf, w2q, b2, dinv, colsumS,
                                              xbuf, stats2, n, 128);
    bn_reduce<<<1, 256, 0, stream>>>(stats2);
    bn_apply_quant_u8<<<gElem128, 256, 0, stream>>>(xbuf, stats2, stats2 + 128,
                                                    bn2g, bn2b, g3, qbuf, n);

    // ---- layer 3: aggregate(q)*W3 + rowsum*b3, softmax fused ----
    aggregate_q8_wave<<<gWave, 256, 0, stream>>>(qbuf, dinv, g3, wtab, 1, startA, indeg,
                                                 ssrc, hbuf, n, E);
    gemm40_softmax<<<gRow128, 256, 0, stream>>>(hbuf, w3q, b3, dinv, colsumS,
                                                outF, n, C, 128);
}